// Round 11
// baseline (176.084 us; speedup 1.0000x reference)
//
#include <hip/hip_runtime.h>
#include <hip/hip_bf16.h>

// Problem dims (fixed by reference)
#define B_ROWS   8192
#define K_DIM    2048
#define OUT_COLS 4096
#define EPS      1e-5f

// m201-faithful 8-phase: 256x256 tile, BK=64, 8 waves (2M x 4N), per-wave 128x64,
// B-fragments in register ping-pong, 1 half-tile staged per phase, vmcnt(4) at odd
// phases, counted lgkm left to the compiler (NO explicit lgkmcnt(0) -- r8's bug).
#define BM 256
#define BN 256
#define BK 64
#define NT (K_DIM / BK)   // 32 K-tiles

using f32x4  = __attribute__((ext_vector_type(4))) float;
using bf16x8 = __attribute__((ext_vector_type(8))) short;   // 8 bf16 = 4 VGPRs

__device__ __forceinline__ unsigned short f2bf_rn(float f) {
    unsigned u = __builtin_bit_cast(unsigned, f);
    u += 0x7FFFu + ((u >> 16) & 1u);   // RNE (inputs finite)
    return (unsigned short)(u >> 16);
}

__global__ void cvt_all(const float* __restrict__ x, const float* __restrict__ w,
                        unsigned short* __restrict__ xb, unsigned short* __restrict__ wb) {
    const int n4x = (B_ROWS * K_DIM) / 4;
    const int n4w = (OUT_COLS * K_DIM) / 4;
    int stride = gridDim.x * blockDim.x;
    for (int i = blockIdx.x * blockDim.x + threadIdx.x; i < n4x + n4w; i += stride) {
        const float4* src; ushort4* dst; int j;
        if (i < n4x) { src = (const float4*)x; dst = (ushort4*)xb; j = i; }
        else         { src = (const float4*)w; dst = (ushort4*)wb; j = i - n4x; }
        float4 v = src[j];
        ushort4 r;
        r.x = f2bf_rn(v.x); r.y = f2bf_rn(v.y); r.z = f2bf_rn(v.z); r.w = f2bf_rn(v.w);
        dst[j] = r;
    }
}

__device__ __forceinline__ void gload16(const unsigned short* src, unsigned short* lds) {
    __builtin_amdgcn_global_load_lds((const __attribute__((address_space(1))) void*)src,
                                     (__attribute__((address_space(3))) void*)lds,
                                     16, 0, 0);
}

// 16-lane row sum via DPP row_ror (pure VALU): all 16 lanes get the total
__device__ __forceinline__ float rowsum16(float v) {
    int x;
    x = __builtin_amdgcn_update_dpp(0, __builtin_bit_cast(int, v), 0x121, 0xF, 0xF, true);
    v += __builtin_bit_cast(float, x);
    x = __builtin_amdgcn_update_dpp(0, __builtin_bit_cast(int, v), 0x122, 0xF, 0xF, true);
    v += __builtin_bit_cast(float, x);
    x = __builtin_amdgcn_update_dpp(0, __builtin_bit_cast(int, v), 0x124, 0xF, 0xF, true);
    v += __builtin_bit_cast(float, x);
    x = __builtin_amdgcn_update_dpp(0, __builtin_bit_cast(int, v), 0x128, 0xF, 0xF, true);
    v += __builtin_bit_cast(float, x);
    return v;
}

// stage one half-tile (128 rows x 64 k) = 2 gloads/thread; linear LDS dest,
// per-row XOR-permuted coalesced global source (round-3/7 proven, 0 conflicts)
#define STA(BUF, H, KT) do {                                                        \
    gload16(Ag + (H)*262144 + (KT)*64 + goff0, &As[BUF][(H)*8192 + lds0]);          \
    gload16(Ag + (H)*262144 + (KT)*64 + goff1, &As[BUF][(H)*8192 + lds1]);          \
  } while (0)
#define STB(BUF, H, KT) do {                                                        \
    gload16(Bg + (H)*262144 + (KT)*64 + goff0, &Bs[BUF][(H)*8192 + lds0]);          \
    gload16(Bg + (H)*262144 + (KT)*64 + goff1, &Bs[BUF][(H)*8192 + lds1]);          \
  } while (0)

// one kk-half of next tile's B fragments (4 x ds_read_b128) into ping-pong regs;
// issued AFTER the same-phase af reads (FIFO: compiler's counted lgkm drains af
// only, these stay outstanding across the phase -- the m201 trick)
#define RD_BH(DST, CURB, KK) do {                                                   \
    _Pragma("unroll") for (int n = 0; n < 4; ++n) {                                 \
      const int ro = browb + n * 16 * BK;                                           \
      DST[n][KK] = *(const bf16x8*)&(CURB)[ro + ((KK) ? colsw1 : colsw0)];          \
    } } while (0)

#define VW4  asm volatile("s_waitcnt vmcnt(4)" ::: "memory")
#define BAR  __builtin_amdgcn_s_barrier()
#define NOP_ ((void)0)

// One phase: af-quad reads [+ bb prefetch] [+ half-tile stage] -> barrier ->
// sched fence -> prio 16xMFMA -> [vmcnt(4)] -> barrier.  NO explicit lgkmcnt.
#define PH(CURA, Q, BB, XRD, STAGE, TAILW) do {                                     \
    bf16x8 af[2][2];                                                                \
    _Pragma("unroll") for (int dm = 0; dm < 2; ++dm) {                              \
      const int ro = arow + (2*(Q)+dm) * 16 * BK;                                   \
      af[dm][0] = *(const bf16x8*)&(CURA)[ro + colsw0];                             \
      af[dm][1] = *(const bf16x8*)&(CURA)[ro + colsw1];                             \
    }                                                                               \
    XRD;                                                                            \
    STAGE;                                                                          \
    __builtin_amdgcn_s_barrier();                                                   \
    __builtin_amdgcn_sched_barrier(0);                                              \
    __builtin_amdgcn_s_setprio(1);                                                  \
    _Pragma("unroll") for (int kk = 0; kk < 2; ++kk)                                \
      _Pragma("unroll") for (int dm = 0; dm < 2; ++dm)                              \
        _Pragma("unroll") for (int n = 0; n < 4; ++n)                               \
          acc[2*(Q)+dm][n] = __builtin_amdgcn_mfma_f32_16x16x32_bf16(               \
              af[dm][kk], BB[n][kk], acc[2*(Q)+dm][n], 0, 0, 0);                    \
    __builtin_amdgcn_s_setprio(0);                                                  \
    TAILW;                                                                          \
    __builtin_amdgcn_s_barrier();                                                   \
  } while (0)

__global__ __launch_bounds__(512, 2) void gemm_gn(const unsigned short* __restrict__ A,
                                                  const unsigned short* __restrict__ Bw,
                                                  const float* __restrict__ bias,
                                                  float* __restrict__ out) {
    __shared__ __align__(16) unsigned short As[2][16384];   // 2 x 32 KB
    __shared__ __align__(16) unsigned short Bs[2][16384];   // 2 x 32 KB
    __shared__ __align__(16) float redbuf[256 * 8];         // 8 KB GN scratch

    const int tid  = threadIdx.x;
    const int lane = tid & 63;
    const int wave = tid >> 6;        // 0..7
    const int wr   = wave >> 2;       // 0..1 (M)
    const int wcn  = wave & 3;        // 0..3 (N)
    const int l16  = lane & 15;
    const int lhi  = lane >> 4;

    // T1: XCD-aware bijective swizzle (512 % 8 == 0)
    const int bid  = blockIdx.x;
    const int swz  = (bid & 7) * (gridDim.x >> 3) + (bid >> 3);
    const int brow = swz >> 4;        // 0..31
    const int bcol = swz & 15;        // 0..15

    // staging offsets: slot f -> row f>>3, chunk (f&7)^(row&7)
    int goff0, goff1, lds0, lds1;
    {
        int f0 = tid;          int r0 = f0 >> 3;
        int f1 = 512 + tid;    int r1 = f1 >> 3;
        goff0 = r0 * K_DIM + (((f0 & 7) ^ (r0 & 7)) * 8);
        goff1 = r1 * K_DIM + (((f1 & 7) ^ (r1 & 7)) * 8);
        lds0  = f0 * 8;
        lds1  = f1 * 8;
    }
    const unsigned short* Ag = A  + (size_t)brow * BM * K_DIM;
    const unsigned short* Bg = Bw + (size_t)bcol * BN * K_DIM;

    // swizzled fragment-read column offsets (ushort units); row&7 == l16&7
    const int colsw0 = (0 * 32 + lhi * 8) ^ ((l16 & 7) << 3);
    const int colsw1 = (1 * 32 + lhi * 8) ^ ((l16 & 7) << 3);
    const int arow   = (wr * 128 + l16) * BK;
    const int browb  = (wcn * 64 + l16) * BK;

    const unsigned short* A0p = &As[0][0];
    const unsigned short* A1p = &As[1][0];
    const unsigned short* B0p = &Bs[0][0];
    const unsigned short* B1p = &Bs[1][0];

    // bias folded into accumulator init
    f32x4 acc[8][4];
    {
        float bv[4];
        #pragma unroll
        for (int n = 0; n < 4; ++n)
            bv[n] = bias[bcol * BN + wcn * 64 + n * 16 + l16];
        #pragma unroll
        for (int m = 0; m < 8; ++m)
            #pragma unroll
            for (int n = 0; n < 4; ++n)
                #pragma unroll
                for (int j = 0; j < 4; ++j)
                    acc[m][n][j] = bv[n];
    }

    bf16x8 bbA[4][2];   // B fragments, even tiles
    bf16x8 bbB[4][2];   // B fragments, odd tiles

    // ---- prologue: A(0)->As0, B(0)->Bs0, B(1)->Bs1; leave B(1)'s 4 in flight
    STA(0, 0, 0); STA(0, 1, 0);
    STB(0, 0, 0); STB(0, 1, 0);
    STB(1, 0, 1); STB(1, 1, 1);
    VW4;                        // A(0), B(0) landed; B(1) = 4 outstanding
    BAR;
    RD_BH(bbA, B0p, 0); RD_BH(bbA, B0p, 1);   // tile-0 B frags -> regs

    // Steady state (FIFO-verified):
    //   P1-end vmcnt(4): drains B(t+1) [read at P2], leaves A(t+1)
    //   P3-end vmcnt(4): drains A(t+1) [read next tile], leaves B(t+2)
    //   every drained load is >=2 phases (~1240+ cyc) old
    #pragma unroll 1
    for (int tt = 0; tt < NT; tt += 2) {
        const int k1 = (tt + 1) & (NT - 1);
        const int k2 = (tt + 2) & (NT - 1);
        const int k3 = (tt + 3) & (NT - 1);
        // ---- tile tt (A from As0, B regs bbA; prefetch bbB from Bs1) ----
        PH(A0p, 0, bbA, NOP_,              STA(1, 0, k1), NOP_);
        PH(A0p, 1, bbA, NOP_,              STA(1, 1, k1), VW4 );
        PH(A0p, 2, bbA, RD_BH(bbB, B1p, 0), STB(0, 0, k2), NOP_);
        PH(A0p, 3, bbA, RD_BH(bbB, B1p, 1), STB(0, 1, k2), VW4 );
        // ---- tile tt+1 (A from As1, B regs bbB; prefetch bbA from Bs0) ----
        PH(A1p, 0, bbB, NOP_,              STA(0, 0, k2), NOP_);
        PH(A1p, 1, bbB, NOP_,              STA(0, 1, k2), VW4 );
        PH(A1p, 2, bbB, RD_BH(bbA, B0p, 0), STB(1, 0, k3), NOP_);
        PH(A1p, 3, bbB, RD_BH(bbA, B0p, 1), STB(1, 1, k3), VW4 );
    }

    // ---- epilogue: GroupNorm over 128-col groups (block-local), clip, store ----
    // pass 1: per-row (s, s2) over this wave's 64 cols; DPP reduce into redbuf.
    // C/D layout (16x16): col = lane&15, row = (lane>>4)*4 + j
    #pragma unroll
    for (int m = 0; m < 8; ++m) {
        #pragma unroll
        for (int j = 0; j < 4; ++j) {
            float s = 0.f, s2 = 0.f;
            #pragma unroll
            for (int n = 0; n < 4; ++n) {
                float v = acc[m][n][j];
                s += v; s2 += v * v;
            }
            s  = rowsum16(s);
            s2 = rowsum16(s2);
            if (l16 == 0) {
                int r = wr * 128 + m * 16 + lhi * 4 + j;
                redbuf[r * 8 + wcn * 2 + 0] = s;
                redbuf[r * 8 + wcn * 2 + 1] = s2;
            }
        }
    }
    // drain in-flight dummy stages (wrapped kt) before kernel end
    asm volatile("s_waitcnt vmcnt(0)" ::: "memory");
    __syncthreads();

    // pass 2: combine wave pair per 128-col group (float4 broadcast), normalize, clip, store
    const int p2 = (wcn & 2) * 2;
    #pragma unroll
    for (int m = 0; m < 8; ++m) {
        #pragma unroll
        for (int j = 0; j < 4; ++j) {
            const int r = wr * 128 + m * 16 + lhi * 4 + j;
            const float4 q = *(const float4*)&redbuf[r * 8 + p2];
            const float mean = (q.x + q.z) * (1.0f / 128.0f);
            const float var  = (q.y + q.w) * (1.0f / 128.0f) - mean * mean;
            const float rstd = rsqrtf(var + EPS);
            float* orow = out + (size_t)(brow * BM + r) * OUT_COLS + bcol * BN + wcn * 64 + l16;
            #pragma unroll
            for (int n = 0; n < 4; ++n) {
                float v = (acc[m][n][j] - mean) * rstd;
                v = fminf(fmaxf(v, -1.0f), 1.0f);
                orow[n * 16] = v;
            }
        }
    }
}

extern "C" void kernel_launch(void* const* d_in, const int* in_sizes, int n_in,
                              void* d_out, int out_size, void* d_ws, size_t ws_size,
                              hipStream_t stream) {
    const float* x    = (const float*)d_in[0];   // [8192][2048]
    const float* w    = (const float*)d_in[1];   // [4096][2048]
    const float* bias = (const float*)d_in[2];   // [4096]
    float* out        = (float*)d_out;           // [8192][4096]

    unsigned short* xb = (unsigned short*)d_ws;
    unsigned short* wb = xb + (size_t)B_ROWS * K_DIM;

    cvt_all<<<3072, 256, 0, stream>>>(x, w, xb, wb);

    dim3 grid((B_ROWS / BM) * (OUT_COLS / BN));   // 32 * 16 = 512
    gemm_gn<<<grid, 512, 0, stream>>>(xb, wb, bias, out);
}

// Round 12
// 155.501 us; speedup vs baseline: 1.1324x; 1.1324x over previous
//
#include <hip/hip_runtime.h>
#include <hip/hip_bf16.h>

// Problem dims (fixed by reference)
#define B_ROWS   8192
#define K_DIM    2048
#define OUT_COLS 4096
#define EPS      1e-5f

// CHAMPION (round-10 structure): 256x256 C-tile, BK=64, 1024 threads = 16 waves
// (4M x 4N), per-wave 64x64, exactly 128 unified regs (64 VGPR + 64 AGPR acc)
// -> 4 waves/SIMD. Double-buffered LDS, stage 1 K-tile ahead, vmcnt(0)+barrier
// once per K-tile (loads age ~2 phases ~3000 cyc >> 900 cyc HBM latency, so the
// drain is stall-free). Proven XOR staging swizzle (0 bank conflicts), T1 XCD
// swizzle, bias-in-acc-init, DPP rowsum epilogue with dedicated redbuf.
#define BM 256
#define BN 256
#define BK 64
#define NT (K_DIM / BK)   // 32 K-tiles

using f32x4  = __attribute__((ext_vector_type(4))) float;
using bf16x8 = __attribute__((ext_vector_type(8))) short;   // 8 bf16 = 4 VGPRs

__device__ __forceinline__ unsigned short f2bf_rn(float f) {
    unsigned u = __builtin_bit_cast(unsigned, f);
    u += 0x7FFFu + ((u >> 16) & 1u);   // RNE (inputs finite)
    return (unsigned short)(u >> 16);
}

__global__ void cvt_all(const float* __restrict__ x, const float* __restrict__ w,
                        unsigned short* __restrict__ xb, unsigned short* __restrict__ wb) {
    const int n4x = (B_ROWS * K_DIM) / 4;
    const int n4w = (OUT_COLS * K_DIM) / 4;
    int stride = gridDim.x * blockDim.x;
    for (int i = blockIdx.x * blockDim.x + threadIdx.x; i < n4x + n4w; i += stride) {
        const float4* src; ushort4* dst; int j;
        if (i < n4x) { src = (const float4*)x; dst = (ushort4*)xb; j = i; }
        else         { src = (const float4*)w; dst = (ushort4*)wb; j = i - n4x; }
        float4 v = src[j];
        ushort4 r;
        r.x = f2bf_rn(v.x); r.y = f2bf_rn(v.y); r.z = f2bf_rn(v.z); r.w = f2bf_rn(v.w);
        dst[j] = r;
    }
}

__device__ __forceinline__ void gload16(const unsigned short* src, unsigned short* lds) {
    __builtin_amdgcn_global_load_lds((const __attribute__((address_space(1))) void*)src,
                                     (__attribute__((address_space(3))) void*)lds,
                                     16, 0, 0);
}

// 16-lane row sum via DPP row_ror (pure VALU): all 16 lanes get the total
__device__ __forceinline__ float rowsum16(float v) {
    int x;
    x = __builtin_amdgcn_update_dpp(0, __builtin_bit_cast(int, v), 0x121, 0xF, 0xF, true);
    v += __builtin_bit_cast(float, x);
    x = __builtin_amdgcn_update_dpp(0, __builtin_bit_cast(int, v), 0x122, 0xF, 0xF, true);
    v += __builtin_bit_cast(float, x);
    x = __builtin_amdgcn_update_dpp(0, __builtin_bit_cast(int, v), 0x124, 0xF, 0xF, true);
    v += __builtin_bit_cast(float, x);
    x = __builtin_amdgcn_update_dpp(0, __builtin_bit_cast(int, v), 0x128, 0xF, 0xF, true);
    v += __builtin_bit_cast(float, x);
    return v;
}

#define VWALL asm volatile("s_waitcnt vmcnt(0)" ::: "memory")
#define BAR   __builtin_amdgcn_s_barrier()

// stage one half-tile (128 rows x 64 k) with 1024 threads = 1 gload/thread;
// linear LDS dest, per-row XOR-permuted coalesced global source (0 conflicts)
#define STA(BUF, H, KT) gload16(Ag + (H)*262144 + (KT)*64 + goffA, &As[BUF][(H)*8192 + ldsA])
#define STB(BUF, H, KT) gload16(Bg + (H)*262144 + (KT)*64 + goffA, &Bs[BUF][(H)*8192 + ldsA])

// one kk-phase: 4 A-frags + 4 B-frags (8 x ds_read_b128, conflict-free) + 16 MFMA
#define PHASE(BUF, CSW) do {                                                        \
    bf16x8 af[4], bb[4];                                                            \
    _Pragma("unroll") for (int m = 0; m < 4; ++m)                                   \
        af[m] = *(const bf16x8*)&As[BUF][abase + m*1024 + (CSW)];                   \
    _Pragma("unroll") for (int n = 0; n < 4; ++n)                                   \
        bb[n] = *(const bf16x8*)&Bs[BUF][bbase + n*1024 + (CSW)];                   \
    __builtin_amdgcn_s_setprio(1);                                                  \
    _Pragma("unroll") for (int m = 0; m < 4; ++m)                                   \
      _Pragma("unroll") for (int n = 0; n < 4; ++n)                                 \
        acc[m][n] = __builtin_amdgcn_mfma_f32_16x16x32_bf16(                        \
            af[m], bb[n], acc[m][n], 0, 0, 0);                                      \
    __builtin_amdgcn_s_setprio(0);                                                  \
  } while (0)

// one K-tile: stage next tile (4 gloads) -> 2 kk-phases -> vmcnt(0) -> barrier.
#define KTILE(BUF, NB, KTN) do {                                                    \
    STA(NB, 0, KTN); STA(NB, 1, KTN);                                               \
    STB(NB, 0, KTN); STB(NB, 1, KTN);                                               \
    PHASE(BUF, csw0);                                                               \
    PHASE(BUF, csw1);                                                               \
    VWALL;                                                                          \
    BAR;                                                                            \
  } while (0)

__global__ __launch_bounds__(1024, 4) void gemm_gn(const unsigned short* __restrict__ A,
                                                   const unsigned short* __restrict__ Bw,
                                                   const float* __restrict__ bias,
                                                   float* __restrict__ out) {
    __shared__ __align__(16) unsigned short As[2][16384];   // 2 x 32 KB
    __shared__ __align__(16) unsigned short Bs[2][16384];   // 2 x 32 KB
    __shared__ __align__(16) float redbuf[256 * 8];         // 8 KB GN scratch

    const int tid  = threadIdx.x;
    const int lane = tid & 63;
    const int wave = tid >> 6;        // 0..15
    const int wr   = wave >> 2;       // 0..3 (M)
    const int wcn  = wave & 3;        // 0..3 (N)
    const int l16  = lane & 15;
    const int lhi  = lane >> 4;

    // T1: XCD-aware bijective swizzle (512 % 8 == 0)
    const int bid  = blockIdx.x;
    const int swz  = (bid & 7) * (gridDim.x >> 3) + (bid >> 3);
    const int brow = swz >> 4;        // 0..31
    const int bcol = swz & 15;        // 0..15

    // staging offsets: slot s = tid (1024 slots/half-tile); row s>>3, chunk (s&7)^(row&7)
    int goffA, ldsA;
    {
        int s = tid;  int r = s >> 3;
        goffA = r * K_DIM + (((s & 7) ^ (r & 7)) * 8);
        ldsA  = s * 8;
    }
    const unsigned short* Ag = A  + (size_t)brow * BM * K_DIM;
    const unsigned short* Bg = Bw + (size_t)bcol * BN * K_DIM;

    // fragment-read offsets: row r, chunk c = kk*4+lhi, physical chunk c^(r&7)
    const int csw0  = ((0 * 4 + lhi) ^ (l16 & 7)) * 8;
    const int csw1  = ((1 * 4 + lhi) ^ (l16 & 7)) * 8;
    const int abase = (wr >> 1) * 8192 + ((wr & 1) * 64 + l16) * 64;
    const int bbase = (wcn >> 1) * 8192 + ((wcn & 1) * 64 + l16) * 64;

    // bias folded into accumulator init
    f32x4 acc[4][4];
    {
        float bv[4];
        #pragma unroll
        for (int n = 0; n < 4; ++n)
            bv[n] = bias[bcol * BN + wcn * 64 + n * 16 + l16];
        #pragma unroll
        for (int m = 0; m < 4; ++m)
            #pragma unroll
            for (int n = 0; n < 4; ++n)
                #pragma unroll
                for (int j = 0; j < 4; ++j)
                    acc[m][n][j] = bv[n];
    }

    // ---- prologue: stage tile 0 only, drain, publish
    STA(0, 0, 0); STA(0, 1, 0);
    STB(0, 0, 0); STB(0, 1, 0);
    VWALL;
    BAR;

    // ---- main loop: 32 K-tiles in 16 statically-buffered pairs;
    // last stage wraps to kt=0 (dummy into buf1's partner, drained in-loop)
    #pragma unroll 1
    for (int it = 0; it < NT / 2; ++it) {
        const int kt = it * 2;
        KTILE(0, 1, kt + 1);
        KTILE(1, 0, (kt + 2) & (NT - 1));
    }

    // ---- epilogue: GroupNorm over 128-col groups (block-local), clip, store ----
    // pass 1: per-row (s, s2) over this wave's 64 cols; DPP reduce into redbuf.
    // C/D layout (16x16): col = lane&15, row = (lane>>4)*4 + j
    #pragma unroll
    for (int m = 0; m < 4; ++m) {
        #pragma unroll
        for (int j = 0; j < 4; ++j) {
            float s = 0.f, s2 = 0.f;
            #pragma unroll
            for (int n = 0; n < 4; ++n) {
                float v = acc[m][n][j];
                s += v; s2 += v * v;
            }
            s  = rowsum16(s);
            s2 = rowsum16(s2);
            if (l16 == 0) {
                int r = wr * 64 + m * 16 + lhi * 4 + j;
                redbuf[r * 8 + wcn * 2 + 0] = s;
                redbuf[r * 8 + wcn * 2 + 1] = s2;
            }
        }
    }
    __syncthreads();

    // pass 2: combine wave pair per 128-col group (float4 broadcast), normalize, clip, store
    const int p2 = (wcn & 2) * 2;
    #pragma unroll
    for (int m = 0; m < 4; ++m) {
        #pragma unroll
        for (int j = 0; j < 4; ++j) {
            const int r = wr * 64 + m * 16 + lhi * 4 + j;
            const float4 q = *(const float4*)&redbuf[r * 8 + p2];
            const float mean = (q.x + q.z) * (1.0f / 128.0f);
            const float var  = (q.y + q.w) * (1.0f / 128.0f) - mean * mean;
            const float rstd = rsqrtf(var + EPS);
            float* orow = out + (size_t)(brow * BM + r) * OUT_COLS + bcol * BN + wcn * 64 + l16;
            #pragma unroll
            for (int n = 0; n < 4; ++n) {
                float v = (acc[m][n][j] - mean) * rstd;
                v = fminf(fmaxf(v, -1.0f), 1.0f);
                orow[n * 16] = v;
            }
        }
    }
}

extern "C" void kernel_launch(void* const* d_in, const int* in_sizes, int n_in,
                              void* d_out, int out_size, void* d_ws, size_t ws_size,
                              hipStream_t stream) {
    const float* x    = (const float*)d_in[0];   // [8192][2048]
    const float* w    = (const float*)d_in[1];   // [4096][2048]
    const float* bias = (const float*)d_in[2];   // [4096]
    float* out        = (float*)d_out;           // [8192][4096]

    unsigned short* xb = (unsigned short*)d_ws;
    unsigned short* wb = xb + (size_t)B_ROWS * K_DIM;

    cvt_all<<<3072, 256, 0, stream>>>(x, w, xb, wb);

    dim3 grid((B_ROWS / BM) * (OUT_COLS / BN));   // 32 * 16 = 512
    gemm_gn<<<grid, 1024, 0, stream>>>(xb, wb, bias, out);
}